// Round 1
// 472.350 us; speedup vs baseline: 1.1411x; 1.1411x over previous
//
#include <hip/hip_runtime.h>
#include <hip/hip_bf16.h>

typedef __hip_bfloat16 bf16;
typedef short s16x8 __attribute__((ext_vector_type(8)));
typedef float f32x4 __attribute__((ext_vector_type(4)));

#define DIM 2048
#define NHEADS 16
#define NKVH 4
#define HD 128
#define KVDIM 512
#define BSZ 4
#define SEQ 2048
#define MROWS (BSZ*SEQ)
#define NQKV (DIM+2*KVDIM)

// -------- async global->LDS, 16B per lane, wave-uniform LDS base --------
__device__ __forceinline__ void gld_lds16(const bf16* g, short* l) {
  __builtin_amdgcn_global_load_lds((__attribute__((address_space(1))) void*)(void*)g,
                                   (__attribute__((address_space(3))) void*)l, 16, 0, 0);
}

// -------- fp32 -> bf16 cast, 8 elems/thread --------
__global__ __launch_bounds__(256) void cast_bf16(const float* __restrict__ src,
                                                 bf16* __restrict__ dst, int n8) {
  int i = blockIdx.x*256 + threadIdx.x;
  if (i >= n8) return;
  const float4* s4 = (const float4*)src;
  float4 a = s4[2*i];
  float4 b = s4[2*i+1];
  union { bf16 h[8]; uint4 u; } o;
  o.h[0] = __float2bfloat16(a.x); o.h[1] = __float2bfloat16(a.y);
  o.h[2] = __float2bfloat16(a.z); o.h[3] = __float2bfloat16(a.w);
  o.h[4] = __float2bfloat16(b.x); o.h[5] = __float2bfloat16(b.y);
  o.h[6] = __float2bfloat16(b.z); o.h[7] = __float2bfloat16(b.w);
  ((uint4*)dst)[i] = o.u;
}

// -------- merged Wq|Wk|Wv cast into contiguous Wqkv --------
__global__ __launch_bounds__(256) void cast_w3(const float* __restrict__ Wq,
                                               const float* __restrict__ Wk,
                                               const float* __restrict__ Wv,
                                               bf16* __restrict__ dst) {
  int i = blockIdx.x*256 + threadIdx.x;          // 8-elem groups; total 786432
  const float* src; int j;
  if (i < 524288)      { src = Wq; j = i; }
  else if (i < 655360) { src = Wk; j = i - 524288; }
  else                 { src = Wv; j = i - 655360; }
  const float4* s4 = (const float4*)src;
  float4 a = s4[2*j];
  float4 b = s4[2*j+1];
  union { bf16 h[8]; uint4 u; } o;
  o.h[0] = __float2bfloat16(a.x); o.h[1] = __float2bfloat16(a.y);
  o.h[2] = __float2bfloat16(a.z); o.h[3] = __float2bfloat16(a.w);
  o.h[4] = __float2bfloat16(b.x); o.h[5] = __float2bfloat16(b.y);
  o.h[6] = __float2bfloat16(b.z); o.h[7] = __float2bfloat16(b.w);
  ((uint4*)dst)[i] = o.u;
}

// ==================== 256x256 / BK=64 / 8-wave / 8-phase GEMM ====================
// C[M,N] = A[M,K] @ B[N,K]^T, bf16 in, fp32 acc. K must be 2048 (32 K-tiles).
// T2: st_16x32 LDS swizzle (subtiled [16][32] layout, XOR byte-bit5 with bit9),
//     applied as inverse-permuted GLOBAL source + swizzled ds_read (linear LDS dest).
// T3+T4: 4 phases/K-tile (one C-quadrant each), 1 half-tile staged per phase,
//     single counted s_waitcnt vmcnt(6) per K-tile (3 half-tiles stay in flight).
// T5: s_setprio(1) around each 16-MFMA cluster.
//
// Staging schedule (K-tile t, buf b=t&1; write always barrier-separated from the
// destination slot's last read):
//   t.1: stage (t+1) A0.L1/A1.L1 -> buf b^1   (slots last read at (t-1).3)
//   t.2: stage (t+2) A0.L0/A1.L0 -> buf b     (rows 0-63 last read at t.1)
//   t.3: stage (t+2) B0.L0/L1    -> buf b     (B last read at t.2)
//   t.4: stage (t+2) B1.L0/L1    -> buf b     (B last read at t.2); vmcnt(6)
// vmcnt(6) at t.4 => everything issued through t.1 has landed => K-tile t+1 complete.

template<int MQ>
__device__ __forceinline__ void lda(s16x8 (&af)[4][2], const short* pa, int rds) {
#pragma unroll
  for (int fr = 0; fr < 4; fr++)
#pragma unroll
    for (int ks = 0; ks < 2; ks++)
      af[fr][ks] = *(const s16x8*)(pa + ((MQ*4 + fr)*2 + ks)*512 + rds);
}
template<int NQ>
__device__ __forceinline__ void ldb(s16x8 (&bfv)[2][2], const short* pb, int bsub, int rds) {
#pragma unroll
  for (int fc = 0; fc < 2; fc++)
#pragma unroll
    for (int ks = 0; ks < 2; ks++)
      bfv[fc][ks] = *(const s16x8*)(pb + (bsub + (NQ*2 + fc)*2 + ks)*512 + rds);
}
template<int MQ, int NQ>
__device__ __forceinline__ void mmq(f32x4 (&acc)[8][4], const s16x8 (&af)[4][2],
                                    const s16x8 (&bfv)[2][2]) {
#pragma unroll
  for (int fr = 0; fr < 4; fr++)
#pragma unroll
    for (int fc = 0; fc < 2; fc++)
#pragma unroll
      for (int ks = 0; ks < 2; ks++)
        acc[MQ*4+fr][NQ*2+fc] = __builtin_amdgcn_mfma_f32_16x16x32_bf16(
            af[fr][ks], bfv[fc][ks], acc[MQ*4+fr][NQ*2+fc], 0, 0, 0);
}

#define WV6 asm volatile("s_waitcnt vmcnt(6)" ::: "memory")
#define WV0 asm volatile("s_waitcnt vmcnt(0)" ::: "memory")
#define WVN ((void)0)
#define GBAR __builtin_amdgcn_s_barrier()
#define WLK asm volatile("s_waitcnt lgkmcnt(0)" ::: "memory")
#define PRI1 __builtin_amdgcn_s_setprio(1)
#define PRI0 __builtin_amdgcn_s_setprio(0)

#define KT(B_, T_, S1_, S2_, WVX) do {                                          \
    const short* pa = pAr[B_];                                                  \
    const short* pb = pBr[B_];                                                  \
    s16x8 af[4][2], b0f[2][2], b1f[2][2];                                       \
    /* phase 1: quad(0,0) */                                                    \
    lda<0>(af, pa, rds); ldb<0>(b0f, pb, bsub, rds);                            \
    if (S1_) {                                                                  \
      gld_lds16(Ab +      (long)((T_)+1)*64 + eA1, &L[1-(B_)][0][4096+wid512]); \
      gld_lds16(Ab + h1 + (long)((T_)+1)*64 + eA1, &L[1-(B_)][1][4096+wid512]); \
    }                                                                           \
    GBAR; WLK; PRI1; mmq<0,0>(acc, af, b0f); PRI0; GBAR;                        \
    /* phase 2: quad(0,1) */                                                    \
    ldb<1>(b1f, pb, bsub, rds);                                                 \
    if (S2_) {                                                                  \
      gld_lds16(Ab +      (long)((T_)+2)*64 + eA0, &L[B_][0][wid512]);          \
      gld_lds16(Ab + h1 + (long)((T_)+2)*64 + eA0, &L[B_][1][wid512]);          \
    }                                                                           \
    GBAR; WLK; PRI1; mmq<0,1>(acc, af, b1f); PRI0; GBAR;                        \
    /* phase 3: quad(1,0) */                                                    \
    lda<1>(af, pa, rds);                                                        \
    if (S2_) {                                                                  \
      gld_lds16(Bb + (long)((T_)+2)*64 + eA0, &L[B_][2][wid512]);               \
      gld_lds16(Bb + (long)((T_)+2)*64 + eA1, &L[B_][2][4096+wid512]);          \
    }                                                                           \
    GBAR; WLK; PRI1; mmq<1,0>(acc, af, b0f); PRI0; GBAR;                        \
    /* phase 4: quad(1,1) */                                                    \
    if (S2_) {                                                                  \
      gld_lds16(Bb + h1 + (long)((T_)+2)*64 + eA0, &L[B_][3][wid512]);          \
      gld_lds16(Bb + h1 + (long)((T_)+2)*64 + eA1, &L[B_][3][4096+wid512]);     \
    }                                                                           \
    WVX;                                                                        \
    GBAR; PRI1; mmq<1,1>(acc, af, b1f); PRI0; GBAR;                             \
  } while (0)

// EPI=0: plain fp32 C.  EPI=1: scatter bf16 into Q[b,h,s,d]/K[b,h,s,d]/V^T[b,kvh,d,s].
template<int EPI>
__global__ __launch_bounds__(512, 2) void gemm8(
    const bf16* __restrict__ A, const bf16* __restrict__ Bm,
    float* __restrict__ Cf, bf16* __restrict__ Qo, bf16* __restrict__ Ko,
    bf16* __restrict__ Vo, int N, int K) {
  // [buf][slot: A-half0, A-half1, B-half0, B-half1][16KB as shorts]
  __shared__ short L[2][4][8192] __attribute__((aligned(16)));
  const int tid = threadIdx.x;
  const int lane = tid & 63, wid = tid >> 6;
  const int quad = lane >> 4, l15 = lane & 15;
  const int wm = wid >> 2, wn = wid & 3;          // 2 M-waves x 4 N-waves
  const int m0 = blockIdx.y * 256, n0 = blockIdx.x * 256;

  // ---- swizzled ds_read lane offset (shorts within a half-tile slot) ----
  // logical (r,c) -> subtile st=(r>>4)*2+(c>>5), byte = st*1024 + (r&15)*64 + (c&31)*2,
  // physical = byte ^ (((byte>>9)&1)<<5); for frag reads bit9 == (l15&8).
  const int rds = l15*32 + ((quad*8) ^ ((l15 & 8) << 1));
  const int bsub = (wn & 1) * 8;                  // B strip within its half: 8 subtiles

  // ---- staging source offsets (inverse-swizzled global address, linear LDS dest) ----
  // lane writes physical 16B at wid*1024 + lane*16 (+ j*8192); inverse swizzle flips
  // col bit for lanes >= 32.
  const int colx = ((lane & 3) * 8) ^ ((lane >> 5) << 4);
  const int gc   = ((wid & 1) << 5) + colx;
  const int gr0  = ((wid >> 1) << 4) + (lane >> 2);
  const long eA0 = (long)gr0 * K + gc;            // j=0 chunk: rows 0-63 of half
  const long eA1 = eA0 + 64L * K;                 // j=1 chunk: rows 64-127
  const int wid512 = wid * 512;
  const bf16* Ab = A  + (long)m0 * K;
  const bf16* Bb = Bm + (long)n0 * K;
  const long h1 = 128L * K;                       // half-1 row offset

  const short* pAr[2] = { &L[0][wm][0], &L[1][wm][0] };
  const short* pBr[2] = { &L[0][2 + (wn >> 1)][0], &L[1][2 + (wn >> 1)][0] };

  f32x4 acc[8][4] = {};

  // ---- prologue: K0 complete (8 chunks) + K1 partial (A-L0s, B: 6 chunks) ----
  gld_lds16(Ab + eA0,           &L[0][0][wid512]);
  gld_lds16(Ab + eA1,           &L[0][0][4096 + wid512]);
  gld_lds16(Ab + h1 + eA0,      &L[0][1][wid512]);
  gld_lds16(Ab + h1 + eA1,      &L[0][1][4096 + wid512]);
  gld_lds16(Bb + eA0,           &L[0][2][wid512]);
  gld_lds16(Bb + eA1,           &L[0][2][4096 + wid512]);
  gld_lds16(Bb + h1 + eA0,      &L[0][3][wid512]);
  gld_lds16(Bb + h1 + eA1,      &L[0][3][4096 + wid512]);
  gld_lds16(Ab + 64 + eA0,      &L[1][0][wid512]);
  gld_lds16(Ab + h1 + 64 + eA0, &L[1][1][wid512]);
  gld_lds16(Bb + 64 + eA0,      &L[1][2][wid512]);
  gld_lds16(Bb + 64 + eA1,      &L[1][2][4096 + wid512]);
  gld_lds16(Bb + h1 + 64 + eA0, &L[1][3][wid512]);
  gld_lds16(Bb + h1 + 64 + eA1, &L[1][3][4096 + wid512]);
  WV6;   // K0's 8 landed; K1's 6 in flight
  GBAR;

  // ---- main loop: 32 K-tiles (K=2048), steady pairs then drained tail ----
  for (int t = 0; t < 30; t += 2) {
    KT(0, t,   1, 1, WV6);
    KT(1, t+1, 1, 1, WV6);
  }
  KT(0, 30, 1, 0, WV0);
  KT(1, 31, 0, 0, WVN);

  // ---- epilogue ----
#pragma unroll
  for (int mi = 0; mi < 8; mi++) {
#pragma unroll
    for (int nj = 0; nj < 4; nj++) {
      const int col = n0 + wn*64 + nj*16 + l15;
#pragma unroll
      for (int r = 0; r < 4; r++) {
        const int row = m0 + wm*128 + mi*16 + quad*4 + r;
        const float v = acc[mi][nj][r];
        if (EPI == 0) {
          Cf[(long)row*N + col] = v;
        } else {
          const int b = row >> 11, s = row & (SEQ-1);
          const bf16 hv = __float2bfloat16(v);
          if (col < DIM) {
            const int h = col >> 7, d = col & 127;
            Qo[((long)(b*NHEADS + h)*SEQ + s)*HD + d] = hv;
          } else if (col < DIM + KVDIM) {
            const int c2 = col - DIM, h = c2 >> 7, d = c2 & 127;
            Ko[((long)(b*NKVH + h)*SEQ + s)*HD + d] = hv;
          } else {
            const int c2 = col - DIM - KVDIM, h = c2 >> 7, d = c2 & 127;
            // V stored TRANSPOSED: [b,kvh,d,s]
            Vo[((long)(b*NKVH + h)*HD + d)*SEQ + s] = hv;
          }
        }
      }
    }
  }
}

// -------- RMSNorm + RoPE (+ q_gain * 1/sqrt(HD)) in-place on bf16 [rows][128] --------
__global__ __launch_bounds__(256) void norm_rope(bf16* __restrict__ Qb,
                                                 bf16* __restrict__ Kb,
                                                 const float* __restrict__ gain) {
  const int lane = threadIdx.x & 63, wid = threadIdx.x >> 6;
  const long rid = (long)blockIdx.x*4 + wid;
  const long QR = (long)BSZ*NHEADS*SEQ;
  bf16* ptr; float g; int s;
  if (rid < QR) {
    ptr = Qb + rid*HD;
    s = (int)(rid & (SEQ-1));
    const int h = (int)((rid >> 11) & 15);
    g = gain[h] * 0.08838834764831845f;   // fold softmax scale 1/sqrt(128) into q
  } else {
    const long r2 = rid - QR;
    ptr = Kb + r2*HD;
    s = (int)(r2 & (SEQ-1));
    g = 1.0f;
  }
  float x1 = __bfloat162float(ptr[lane]);
  float x2 = __bfloat162float(ptr[lane+64]);
  float ss = x1*x1 + x2*x2;
#pragma unroll
  for (int off = 1; off < 64; off <<= 1) ss += __shfl_xor(ss, off);
  const float rn = rsqrtf(ss*(1.0f/128.0f) + 1.1920928955078125e-07f);
  const float inv_freq = exp2f((float)lane * -0.20762050593046014f);
  float sn, cs;
  sincosf((float)s * inv_freq, &sn, &cs);
  const float q1 = x1*rn, q2 = x2*rn;
  ptr[lane]    = __float2bfloat16((q1*cs + q2*sn)*g);
  ptr[lane+64] = __float2bfloat16((q2*cs - q1*sn)*g);
}

// -------- causal flash attention: S^T form, fixed-shift softmax, qt-paired --------
// Block x handles query-tiles qt=15-x then qt=x: 34 key-tiles for EVERY block ->
// perfect balance, grid 8x64=512 blocks = exactly 2/CU, one dispatch round.
// NOTE round-4 lesson: register K/V prefetch spilled to scratch (WRITE_SIZE 32->456MB,
// 237us). Staging stays as plain in-loop global->VGPR->ds_write (108-reg allocation).
__global__ __launch_bounds__(256, 2) void attn(
    const bf16* __restrict__ Qb, const bf16* __restrict__ Kb,
    const bf16* __restrict__ Vtg, bf16* __restrict__ Yb) {
  __shared__ short Kt[64*136]  __attribute__((aligned(16)));  // [key][k] pad->136
  __shared__ short Vt[128*72]  __attribute__((aligned(16)));  // [d][key] pad->72
  __shared__ short Pt[4*2304]  __attribute__((aligned(16)));  // per-wave, per-group [16 q][72]

  const int tid = threadIdx.x;
  const int lane = tid & 63, wid = tid >> 6;
  const int quad = lane >> 4, l15 = lane & 15;
  const int xb = blockIdx.x;                    // 0..7
  const int bh = blockIdx.y;
  const int b = bh >> 4, h = bh & 15, kvh = h >> 2;

  const bf16* kbase = Kb  + (long)(b*NKVH + kvh)*SEQ*HD;
  const bf16* vbase = Vtg + (long)(b*NKVH + kvh)*HD*SEQ;   // [d][s]
  short* pw0 = Pt + wid*2304;
  short* pw1 = pw0 + 1152;
  const int krow = tid >> 4, kc = (tid & 15)*8;
  const int vrow = tid >> 3, vc = (tid & 7)*8;

  for (int phase = 0; phase < 2; phase++) {
    const int qt = phase ? xb : (15 - xb);      // heavy first
    const int q0 = qt*128 + wid*16 + l15;       // group 0 query
    const int q1 = q0 + 64;                     // group 1 query
    const bf16* qr0 = Qb + ((long)(b*NHEADS + h)*SEQ + q0)*HD + quad*8;
    s16x8 qa0[4], qa1[4];
#pragma unroll
    for (int st = 0; st < 4; st++) {
      qa0[st] = *(const s16x8*)(qr0 + st*32);
      qa1[st] = *(const s16x8*)(qr0 + 64*HD + st*32);
    }

    f32x4 o0[8] = {}, o1[8] = {};
    float li0 = 0.0f, li1 = 0.0f;
    const int ktiles = 2*qt + 2;

    for (int kt = 0; kt < ktiles; kt++) {
      __syncthreads();
      // stage K tile [64][128] and V^T tile [128][64] (vectorized, conflict-audited)
#pragma unroll
      for (int i = 0; i < 4; i++) {
        uint4 kv = *(const uint4*)(kbase + (long)(kt*64 + i*16 + krow)*HD + kc);
        *(uint4*)&Kt[(i*16 + krow)*136 + kc] = kv;
      }
#pragma unroll
      for (int i = 0; i < 4; i++) {
        uint4 vv = *(const uint4*)(vbase + (long)(i*32 + vrow)*SEQ + kt*64 + vc);
        *(uint4*)&Vt[(i*32 + vrow)*72 + vc] = vv;
      }
      __syncthreads();

      // S^T = K Q^T for both groups; kf frags shared
      f32x4 s0[4] = {}, s1[4] = {};
#pragma unroll
      for (int nt = 0; nt < 4; nt++) {
        s16x8 kf[4];
#pragma unroll
        for (int st = 0; st < 4; st++)
          kf[st] = *(const s16x8*)&Kt[(nt*16 + l15)*136 + st*32 + quad*8];
#pragma unroll
        for (int st = 0; st < 4; st++) {
          s0[nt] = __builtin_amdgcn_mfma_f32_16x16x32_bf16(kf[st], qa0[st], s0[nt], 0, 0, 0);
          s1[nt] = __builtin_amdgcn_mfma_f32_16x16x32_bf16(kf[st], qa1[st], s1[nt], 0, 0, 0);
        }
      }

      // fixed-shift softmax: P = exp(s - 12); |s|<11.5 provably (rms-normed q,k)
      const bool d0 = (kt >= 2*qt);
      const bool d1 = (kt >  2*qt);
      const int tb = kt*64 + quad*4;
      union { bf16 h[16]; unsigned long long u[4]; } p0, p1;
      float rs0 = 0.0f, rs1 = 0.0f;
#pragma unroll
      for (int nt = 0; nt < 4; nt++) {
#pragma unroll
        for (int r = 0; r < 4; r++) {
          const int t = tb + nt*16 + r;
          float v0 = s0[nt][r], v1 = s1[nt][r];
          if (d0 && (t > q0)) v0 = -1e30f;
          if (d1 && (t > q1)) v1 = -1e30f;
          const float e0 = __expf(v0 - 12.0f);
          const float e1 = __expf(v1 - 12.0f);
          rs0 += e0; rs1 += e1;
          p0.h[nt*4+r] = __float2bfloat16(e0);
          p1.h[nt*4+r] = __float2bfloat16(e1);
        }
      }
      li0 += rs0; li1 += rs1;
#pragma unroll
      for (int nt = 0; nt < 4; nt++) {
        *(unsigned long long*)&pw0[l15*72 + nt*16 + quad*4] = p0.u[nt];
        *(unsigned long long*)&pw1[l15*72 + nt*16 + quad*4] = p1.u[nt];
      }

      // O^T += V^T P^T for both groups; vf frags shared
#pragma unroll
      for (int st = 0; st < 2; st++) {
        s16x8 pf0 = *(const s16x8*)&pw0[l15*72 + st*32 + quad*8];
        s16x8 pf1 = *(const s16x8*)&pw1[l15*72 + st*32 + quad*8];
#pragma unroll
        for (int dt = 0; dt < 8; dt++) {
          s16x8 vf = *(const s16x8*)&Vt[(dt*16 + l15)*72 + st*32 + quad*8];
          o0[dt] = __builtin_amdgcn_mfma_f32_16x16x32_bf16(vf, pf0, o0[dt], 0, 0, 0);
          o1[dt] = __builtin_amdgcn_mfma_f32_16x16x32_bf16(vf, pf1, o1[dt], 0, 0, 0);
        }
      }
    }

    // finalize li (once per phase), then transpose O^T -> O via wave-private Pt slice
    li0 += __shfl_xor(li0, 16); li0 += __shfl_xor(li0, 32);
    li1 += __shfl_xor(li1, 16); li1 += __shfl_xor(li1, 32);
    const float inv0 = 1.0f / li0, inv1 = 1.0f / li1;

    short* ep = pw0;
#pragma unroll
    for (int g = 0; g < 2; g++) {
      const float inv = g ? inv1 : inv0;
      const f32x4* o = g ? o1 : o0;
      const int qg = g ? q1 : q0;
#pragma unroll
      for (int dt = 0; dt < 8; dt++) {
        union { bf16 h[4]; unsigned long long u; } pk;
        pk.h[0] = __float2bfloat16(o[dt][0]*inv);
        pk.h[1] = __float2bfloat16(o[dt][1]*inv);
        pk.h[2] = __float2bfloat16(o[dt][2]*inv);
        pk.h[3] = __float2bfloat16(o[dt][3]*inv);
        *(unsigned long long*)&ep[l15*136 + dt*16 + quad*4] = pk.u;
      }
      bf16* yb = Yb + ((long)(b*SEQ + qg - l15))*DIM + h*HD;
#pragma unroll
      for (int p = 0; p < 4; p++) {
        const int c = quad + 4*p;
        uint4 yv = *(const uint4*)&ep[l15*136 + c*8];
        *(uint4*)&yb[(long)l15*DIM + c*8] = yv;
      }
    }
  }
}

extern "C" void kernel_launch(void* const* d_in, const int* in_sizes, int n_in,
                              void* d_out, int out_size, void* d_ws, size_t ws_size,
                              hipStream_t stream) {
  (void)in_sizes; (void)n_in; (void)out_size; (void)ws_size;
  const float* x   = (const float*)d_in[0];
  const float* Wq  = (const float*)d_in[1];
  const float* Wk  = (const float*)d_in[2];
  const float* Wv  = (const float*)d_in[3];
  const float* Wo  = (const float*)d_in[4];
  const float* qg  = (const float*)d_in[5];

  char* ws = (char*)d_ws;
  bf16* xbf  = (bf16*)(ws);                         // 32 MB
  bf16* Wqkv = (bf16*)(ws + 33554432);              // 12 MB
  bf16* Wob  = (bf16*)(ws + 46137344);              //  8 MB
  bf16* Qb   = (bf16*)(ws + 54525952);              // 32 MB
  bf16* Kb   = (bf16*)(ws + 88080384);              //  8 MB
  bf16* Vb   = (bf16*)(ws + 96468992);              //  8 MB (transposed [b,kvh,d,s])
  bf16* Yb   = (bf16*)(ws + 104857600);             // 32 MB

  cast_bf16<<<8192, 256, 0, stream>>>(x,  xbf, MROWS*DIM/8);
  cast_w3<<<3072, 256, 0, stream>>>(Wq, Wk, Wv, Wqkv);
  cast_bf16<<<2048, 256, 0, stream>>>(Wo, Wob, DIM*DIM/8);

  gemm8<1><<<dim3(NQKV/256, MROWS/256), 512, 0, stream>>>(
      xbf, Wqkv, nullptr, Qb, Kb, Vb, NQKV, DIM);

  norm_rope<<<40960, 256, 0, stream>>>(Qb, Kb, qg);

  attn<<<dim3(8, BSZ*NHEADS), 256, 0, stream>>>(Qb, Kb, Vb, Yb);

  gemm8<0><<<dim3(DIM/256, MROWS/256), 512, 0, stream>>>(
      Yb, Wob, (float*)d_out, nullptr, nullptr, nullptr, DIM, DIM);
}

// Round 2
// 439.409 us; speedup vs baseline: 1.2266x; 1.0750x over previous
//
#include <hip/hip_runtime.h>
#include <hip/hip_bf16.h>

typedef __hip_bfloat16 bf16;
typedef short s16x8 __attribute__((ext_vector_type(8)));
typedef float f32x4 __attribute__((ext_vector_type(4)));

#define DIM 2048
#define NHEADS 16
#define NKVH 4
#define HD 128
#define KVDIM 512
#define BSZ 4
#define SEQ 2048
#define MROWS (BSZ*SEQ)
#define NQKV (DIM+2*KVDIM)

// -------- async global->LDS, 16B per lane, wave-uniform LDS base --------
__device__ __forceinline__ void gld_lds16(const bf16* g, short* l) {
  __builtin_amdgcn_global_load_lds((__attribute__((address_space(1))) void*)(void*)g,
                                   (__attribute__((address_space(3))) void*)l, 16, 0, 0);
}

// -------- single fused fp32 -> bf16 cast for all five tensors --------
// groups of 8 elems: x 2097152 | Wq 524288 | Wk 131072 | Wv 131072 | Wo 524288
__global__ __launch_bounds__(256) void cast_all(
    const float* __restrict__ x,  const float* __restrict__ Wq,
    const float* __restrict__ Wk, const float* __restrict__ Wv,
    const float* __restrict__ Wo, bf16* __restrict__ xbf,
    bf16* __restrict__ Wqkv, bf16* __restrict__ Wob) {
  const int i = blockIdx.x*256 + threadIdx.x;      // 13312*256 = 3407872 exact
  const float* src; bf16* dst; int j, o;
  if (i < 2097152)      { src = x;  dst = xbf;  j = i;           o = i; }
  else if (i < 2621440) { src = Wq; dst = Wqkv; j = i - 2097152; o = i - 2097152; }
  else if (i < 2752512) { src = Wk; dst = Wqkv; j = i - 2621440; o = i - 2097152; }
  else if (i < 2883584) { src = Wv; dst = Wqkv; j = i - 2752512; o = i - 2097152; }
  else                  { src = Wo; dst = Wob;  j = i - 2883584; o = i - 2883584; }
  const float4* s4 = (const float4*)src;
  float4 a = s4[2*j];
  float4 b = s4[2*j+1];
  union { bf16 h[8]; uint4 u; } pk;
  pk.h[0] = __float2bfloat16(a.x); pk.h[1] = __float2bfloat16(a.y);
  pk.h[2] = __float2bfloat16(a.z); pk.h[3] = __float2bfloat16(a.w);
  pk.h[4] = __float2bfloat16(b.x); pk.h[5] = __float2bfloat16(b.y);
  pk.h[6] = __float2bfloat16(b.z); pk.h[7] = __float2bfloat16(b.w);
  ((uint4*)dst)[o] = pk.u;
}

// ==================== 256x256 / BK=64 / 8-wave / 8-phase GEMM ====================
// C[M,N] = A[M,K] @ B[N,K]^T, bf16 in, fp32 acc. K must be 2048 (32 K-tiles).
// T1: bijective XCD swizzle (both grids %8==0) - row-chunk per XCD L2.
// T2: st_16x32 LDS swizzle, inverse-permuted GLOBAL source + swizzled ds_read.
// T3+T4: 4 phases/K-tile, 1 half-tile staged per phase, single vmcnt(6)/K-tile.
// T5: s_setprio(1) around each 16-MFMA cluster.
// EPI=1 epilogue: Q/K via wave-private LDS transpose -> 16B coalesced stores;
//                 V via packed 8B stores (s is the register-contiguous axis).

template<int MQ>
__device__ __forceinline__ void lda(s16x8 (&af)[4][2], const short* pa, int rds) {
#pragma unroll
  for (int fr = 0; fr < 4; fr++)
#pragma unroll
    for (int ks = 0; ks < 2; ks++)
      af[fr][ks] = *(const s16x8*)(pa + ((MQ*4 + fr)*2 + ks)*512 + rds);
}
template<int NQ>
__device__ __forceinline__ void ldb(s16x8 (&bfv)[2][2], const short* pb, int bsub, int rds) {
#pragma unroll
  for (int fc = 0; fc < 2; fc++)
#pragma unroll
    for (int ks = 0; ks < 2; ks++)
      bfv[fc][ks] = *(const s16x8*)(pb + (bsub + (NQ*2 + fc)*2 + ks)*512 + rds);
}
template<int MQ, int NQ>
__device__ __forceinline__ void mmq(f32x4 (&acc)[8][4], const s16x8 (&af)[4][2],
                                    const s16x8 (&bfv)[2][2]) {
#pragma unroll
  for (int fr = 0; fr < 4; fr++)
#pragma unroll
    for (int fc = 0; fc < 2; fc++)
#pragma unroll
      for (int ks = 0; ks < 2; ks++)
        acc[MQ*4+fr][NQ*2+fc] = __builtin_amdgcn_mfma_f32_16x16x32_bf16(
            af[fr][ks], bfv[fc][ks], acc[MQ*4+fr][NQ*2+fc], 0, 0, 0);
}

#define WV6 asm volatile("s_waitcnt vmcnt(6)" ::: "memory")
#define WV0 asm volatile("s_waitcnt vmcnt(0)" ::: "memory")
#define WVN ((void)0)
#define GBAR __builtin_amdgcn_s_barrier()
#define WLK asm volatile("s_waitcnt lgkmcnt(0)" ::: "memory")
#define PRI1 __builtin_amdgcn_s_setprio(1)
#define PRI0 __builtin_amdgcn_s_setprio(0)

#define KT(B_, T_, S1_, S2_, WVX) do {                                          \
    const short* pa = pAr[B_];                                                  \
    const short* pb = pBr[B_];                                                  \
    s16x8 af[4][2], b0f[2][2], b1f[2][2];                                       \
    /* phase 1: quad(0,0) */                                                    \
    lda<0>(af, pa, rds); ldb<0>(b0f, pb, bsub, rds);                            \
    if (S1_) {                                                                  \
      gld_lds16(Ab +      (long)((T_)+1)*64 + eA1, &L[1-(B_)][0][4096+wid512]); \
      gld_lds16(Ab + h1 + (long)((T_)+1)*64 + eA1, &L[1-(B_)][1][4096+wid512]); \
    }                                                                           \
    GBAR; WLK; PRI1; mmq<0,0>(acc, af, b0f); PRI0; GBAR;                        \
    /* phase 2: quad(0,1) */                                                    \
    ldb<1>(b1f, pb, bsub, rds);                                                 \
    if (S2_) {                                                                  \
      gld_lds16(Ab +      (long)((T_)+2)*64 + eA0, &L[B_][0][wid512]);          \
      gld_lds16(Ab + h1 + (long)((T_)+2)*64 + eA0, &L[B_][1][wid512]);          \
    }                                                                           \
    GBAR; WLK; PRI1; mmq<0,1>(acc, af, b1f); PRI0; GBAR;                        \
    /* phase 3: quad(1,0) */                                                    \
    lda<1>(af, pa, rds);                                                        \
    if (S2_) {                                                                  \
      gld_lds16(Bb + (long)((T_)+2)*64 + eA0, &L[B_][2][wid512]);               \
      gld_lds16(Bb + (long)((T_)+2)*64 + eA1, &L[B_][2][4096+wid512]);          \
    }                                                                           \
    GBAR; WLK; PRI1; mmq<1,0>(acc, af, b0f); PRI0; GBAR;                        \
    /* phase 4: quad(1,1) */                                                    \
    if (S2_) {                                                                  \
      gld_lds16(Bb + h1 + (long)((T_)+2)*64 + eA0, &L[B_][3][wid512]);          \
      gld_lds16(Bb + h1 + (long)((T_)+2)*64 + eA1, &L[B_][3][4096+wid512]);     \
    }                                                                           \
    WVX;                                                                        \
    GBAR; PRI1; mmq<1,1>(acc, af, b1f); PRI0; GBAR;                             \
  } while (0)

// EPI=0: plain fp32 C.  EPI=1: scatter bf16 into Q[b,h,s,d]/K[b,h,s,d]/V^T[b,kvh,d,s].
template<int EPI>
__global__ __launch_bounds__(512, 2) void gemm8(
    const bf16* __restrict__ A, const bf16* __restrict__ Bm,
    float* __restrict__ Cf, bf16* __restrict__ Qo, bf16* __restrict__ Ko,
    bf16* __restrict__ Vo, int N, int K) {
  // [buf][slot: A-half0, A-half1, B-half0, B-half1][16KB as shorts]
  __shared__ short L[2][4][8192] __attribute__((aligned(16)));
  const int tid = threadIdx.x;
  const int lane = tid & 63, wid = tid >> 6;
  const int quad = lane >> 4, l15 = lane & 15;
  const int wm = wid >> 2, wn = wid & 3;          // 2 M-waves x 4 N-waves

  // ---- T1: bijective XCD swizzle (nwg % 8 == 0 for both grids) ----
  const int gx  = gridDim.x;
  const int lin = blockIdx.y * gx + blockIdx.x;
  const int cpx = (gx * gridDim.y) >> 3;
  const int swz = (lin & 7) * cpx + (lin >> 3);
  const int m0 = (swz / gx) * 256, n0 = (swz % gx) * 256;

  // ---- swizzled ds_read lane offset (shorts within a half-tile slot) ----
  const int rds = l15*32 + ((quad*8) ^ ((l15 & 8) << 1));
  const int bsub = (wn & 1) * 8;                  // B strip within its half: 8 subtiles

  // ---- staging source offsets (inverse-swizzled global address, linear LDS dest) ----
  const int colx = ((lane & 3) * 8) ^ ((lane >> 5) << 4);
  const int gc   = ((wid & 1) << 5) + colx;
  const int gr0  = ((wid >> 1) << 4) + (lane >> 2);
  const long eA0 = (long)gr0 * K + gc;            // j=0 chunk: rows 0-63 of half
  const long eA1 = eA0 + 64L * K;                 // j=1 chunk: rows 64-127
  const int wid512 = wid * 512;
  const bf16* Ab = A  + (long)m0 * K;
  const bf16* Bb = Bm + (long)n0 * K;
  const long h1 = 128L * K;                       // half-1 row offset

  const short* pAr[2] = { &L[0][wm][0], &L[1][wm][0] };
  const short* pBr[2] = { &L[0][2 + (wn >> 1)][0], &L[1][2 + (wn >> 1)][0] };

  f32x4 acc[8][4] = {};

  // ---- prologue: K0 complete (8 chunks) + K1 partial (A-L0s, B: 6 chunks) ----
  gld_lds16(Ab + eA0,           &L[0][0][wid512]);
  gld_lds16(Ab + eA1,           &L[0][0][4096 + wid512]);
  gld_lds16(Ab + h1 + eA0,      &L[0][1][wid512]);
  gld_lds16(Ab + h1 + eA1,      &L[0][1][4096 + wid512]);
  gld_lds16(Bb + eA0,           &L[0][2][wid512]);
  gld_lds16(Bb + eA1,           &L[0][2][4096 + wid512]);
  gld_lds16(Bb + h1 + eA0,      &L[0][3][wid512]);
  gld_lds16(Bb + h1 + eA1,      &L[0][3][4096 + wid512]);
  gld_lds16(Ab + 64 + eA0,      &L[1][0][wid512]);
  gld_lds16(Ab + h1 + 64 + eA0, &L[1][1][wid512]);
  gld_lds16(Bb + 64 + eA0,      &L[1][2][wid512]);
  gld_lds16(Bb + 64 + eA1,      &L[1][2][4096 + wid512]);
  gld_lds16(Bb + h1 + 64 + eA0, &L[1][3][wid512]);
  gld_lds16(Bb + h1 + 64 + eA1, &L[1][3][4096 + wid512]);
  WV6;   // K0's 8 landed; K1's 6 in flight
  GBAR;

  // ---- main loop: 32 K-tiles (K=2048), steady pairs then drained tail ----
  for (int t = 0; t < 30; t += 2) {
    KT(0, t,   1, 1, WV6);
    KT(1, t+1, 1, 1, WV6);
  }
  KT(0, 30, 1, 0, WV0);
  KT(1, 31, 0, 0, WVN);

  // ---- epilogue ----
  const int colg0 = n0 + wn*64;                   // wave's first output column
  const int bb = (m0 + wm*128) >> 11;             // batch (tile never crosses)
  const int sb = (m0 + wm*128) & (SEQ-1);         // seq base of wave's 128 rows
  if (EPI == 0) {
#pragma unroll
    for (int mi = 0; mi < 8; mi++)
#pragma unroll
      for (int nj = 0; nj < 4; nj++) {
        const int col = colg0 + nj*16 + l15;
#pragma unroll
        for (int r = 0; r < 4; r++)
          Cf[(long)(m0 + wm*128 + mi*16 + quad*4 + r)*N + col] = acc[mi][nj][r];
      }
  } else if (colg0 >= DIM + KVDIM) {
    // V region: 4 s-contiguous rows per acc quad -> one 8B store each
    const int cv = colg0 - (DIM + KVDIM);
    const int h  = cv >> 7;                       // wave-uniform (cv%128+63 < 128)
    const int db = cv & 127;
    bf16* vb = Vo + ((long)(bb*NKVH + h)*HD)*SEQ + sb;
#pragma unroll
    for (int mi = 0; mi < 8; mi++)
#pragma unroll
      for (int nj = 0; nj < 4; nj++) {
        const int d = db + nj*16 + l15;
        union { bf16 h4[4]; unsigned long long u; } pk;
        pk.h4[0] = __float2bfloat16(acc[mi][nj][0]);
        pk.h4[1] = __float2bfloat16(acc[mi][nj][1]);
        pk.h4[2] = __float2bfloat16(acc[mi][nj][2]);
        pk.h4[3] = __float2bfloat16(acc[mi][nj][3]);
        *(unsigned long long*)(vb + (long)d*SEQ + mi*16 + quad*4) = pk.u;
      }
  } else {
    // Q/K region: wave-private LDS transpose -> coalesced 16B row stores
    short* ew = &L[0][0][0] + wid*8192;           // 16KB slice: [row 0..127][col 0..63]
#pragma unroll
    for (int mi = 0; mi < 8; mi++)
#pragma unroll
      for (int nj = 0; nj < 4; nj++)
#pragma unroll
        for (int r = 0; r < 4; r++) {
          bf16 hv = __float2bfloat16(acc[mi][nj][r]);
          ew[(mi*16 + quad*4 + r)*64 + nj*16 + l15] = *(short*)&hv;
        }
    asm volatile("" ::: "memory");                // pin write->read order
    bf16* gb;
    if (colg0 < DIM) gb = Qo + (long)(bb*NHEADS + (colg0 >> 7))*SEQ*HD;
    else             gb = Ko + (long)(bb*NKVH + ((colg0 - DIM) >> 7))*SEQ*HD;
    const int db = colg0 & 127;                   // 0 or 64
    const int rr = lane >> 3, c8 = (lane & 7)*8;
#pragma unroll
    for (int it = 0; it < 16; it++) {
      const int row = it*8 + rr;
      uint4 v = *(const uint4*)&ew[row*64 + c8];
      *(uint4*)(gb + (long)(sb + row)*HD + db + c8) = v;
    }
  }
}

// -------- RMSNorm + RoPE (+ q_gain * 1/sqrt(HD)) in-place on bf16 [rows][128] --------
__global__ __launch_bounds__(256) void norm_rope(bf16* __restrict__ Qb,
                                                 bf16* __restrict__ Kb,
                                                 const float* __restrict__ gain) {
  const int lane = threadIdx.x & 63, wid = threadIdx.x >> 6;
  const long rid = (long)blockIdx.x*4 + wid;
  const long QR = (long)BSZ*NHEADS*SEQ;
  bf16* ptr; float g; int s;
  if (rid < QR) {
    ptr = Qb + rid*HD;
    s = (int)(rid & (SEQ-1));
    const int h = (int)((rid >> 11) & 15);
    g = gain[h] * 0.08838834764831845f;   // fold softmax scale 1/sqrt(128) into q
  } else {
    const long r2 = rid - QR;
    ptr = Kb + r2*HD;
    s = (int)(r2 & (SEQ-1));
    g = 1.0f;
  }
  float x1 = __bfloat162float(ptr[lane]);
  float x2 = __bfloat162float(ptr[lane+64]);
  float ss = x1*x1 + x2*x2;
#pragma unroll
  for (int off = 1; off < 64; off <<= 1) ss += __shfl_xor(ss, off);
  const float rn = rsqrtf(ss*(1.0f/128.0f) + 1.1920928955078125e-07f);
  const float inv_freq = exp2f((float)lane * -0.20762050593046014f);
  float sn, cs;
  sincosf((float)s * inv_freq, &sn, &cs);
  const float q1 = x1*rn, q2 = x2*rn;
  ptr[lane]    = __float2bfloat16((q1*cs + q2*sn)*g);
  ptr[lane+64] = __float2bfloat16((q2*cs - q1*sn)*g);
}

// -------- causal flash attention: S^T form, fixed-shift softmax, qt-paired --------
__global__ __launch_bounds__(256, 2) void attn(
    const bf16* __restrict__ Qb, const bf16* __restrict__ Kb,
    const bf16* __restrict__ Vtg, bf16* __restrict__ Yb) {
  __shared__ short Kt[64*136]  __attribute__((aligned(16)));  // [key][k] pad->136
  __shared__ short Vt[128*72]  __attribute__((aligned(16)));  // [d][key] pad->72
  __shared__ short Pt[4*2304]  __attribute__((aligned(16)));  // per-wave, per-group [16 q][72]

  const int tid = threadIdx.x;
  const int lane = tid & 63, wid = tid >> 6;
  const int quad = lane >> 4, l15 = lane & 15;
  const int xb = blockIdx.x;                    // 0..7
  const int bh = blockIdx.y;
  const int b = bh >> 4, h = bh & 15, kvh = h >> 2;

  const bf16* kbase = Kb  + (long)(b*NKVH + kvh)*SEQ*HD;
  const bf16* vbase = Vtg + (long)(b*NKVH + kvh)*HD*SEQ;   // [d][s]
  short* pw0 = Pt + wid*2304;
  short* pw1 = pw0 + 1152;
  const int krow = tid >> 4, kc = (tid & 15)*8;
  const int vrow = tid >> 3, vc = (tid & 7)*8;

  for (int phase = 0; phase < 2; phase++) {
    const int qt = phase ? xb : (15 - xb);      // heavy first
    const int q0 = qt*128 + wid*16 + l15;       // group 0 query
    const int q1 = q0 + 64;                     // group 1 query
    const bf16* qr0 = Qb + ((long)(b*NHEADS + h)*SEQ + q0)*HD + quad*8;
    s16x8 qa0[4], qa1[4];
#pragma unroll
    for (int st = 0; st < 4; st++) {
      qa0[st] = *(const s16x8*)(qr0 + st*32);
      qa1[st] = *(const s16x8*)(qr0 + 64*HD + st*32);
    }

    f32x4 o0[8] = {}, o1[8] = {};
    float li0 = 0.0f, li1 = 0.0f;
    const int ktiles = 2*qt + 2;

    for (int kt = 0; kt < ktiles; kt++) {
      __syncthreads();
      // stage K tile [64][128] and V^T tile [128][64] (vectorized, conflict-audited)
#pragma unroll
      for (int i = 0; i < 4; i++) {
        uint4 kv = *(const uint4*)(kbase + (long)(kt*64 + i*16 + krow)*HD + kc);
        *(uint4*)&Kt[(i*16 + krow)*136 + kc] = kv;
      }
#pragma unroll
      for (int i = 0; i < 4; i++) {
        uint4 vv = *(const uint4*)(vbase + (long)(i*32 + vrow)*SEQ + kt*64 + vc);
        *(uint4*)&Vt[(i*32 + vrow)*72 + vc] = vv;
      }
      __syncthreads();

      // S^T = K Q^T for both groups; kf frags shared
      f32x4 s0[4] = {}, s1[4] = {};
#pragma unroll
      for (int nt = 0; nt < 4; nt++) {
        s16x8 kf[4];
#pragma unroll
        for (int st = 0; st < 4; st++)
          kf[st] = *(const s16x8*)&Kt[(nt*16 + l15)*136 + st*32 + quad*8];
#pragma unroll
        for (int st = 0; st < 4; st++) {
          s0[nt] = __builtin_amdgcn_mfma_f32_16x16x32_bf16(kf[st], qa0[st], s0[nt], 0, 0, 0);
          s1[nt] = __builtin_amdgcn_mfma_f32_16x16x32_bf16(kf[st], qa1[st], s1[nt], 0, 0, 0);
        }
      }

      // fixed-shift softmax: P = exp(s - 12); |s|<11.5 provably (rms-normed q,k)
      const bool d0 = (kt >= 2*qt);
      const bool d1 = (kt >  2*qt);
      const int tb = kt*64 + quad*4;
      union { bf16 h[16]; unsigned long long u[4]; } p0, p1;
      float rs0 = 0.0f, rs1 = 0.0f;
#pragma unroll
      for (int nt = 0; nt < 4; nt++) {
#pragma unroll
        for (int r = 0; r < 4; r++) {
          const int t = tb + nt*16 + r;
          float v0 = s0[nt][r], v1 = s1[nt][r];
          if (d0 && (t > q0)) v0 = -1e30f;
          if (d1 && (t > q1)) v1 = -1e30f;
          const float e0 = __expf(v0 - 12.0f);
          const float e1 = __expf(v1 - 12.0f);
          rs0 += e0; rs1 += e1;
          p0.h[nt*4+r] = __float2bfloat16(e0);
          p1.h[nt*4+r] = __float2bfloat16(e1);
        }
      }
      li0 += rs0; li1 += rs1;
#pragma unroll
      for (int nt = 0; nt < 4; nt++) {
        *(unsigned long long*)&pw0[l15*72 + nt*16 + quad*4] = p0.u[nt];
        *(unsigned long long*)&pw1[l15*72 + nt*16 + quad*4] = p1.u[nt];
      }

      // O^T += V^T P^T for both groups; vf frags shared
#pragma unroll
      for (int st = 0; st < 2; st++) {
        s16x8 pf0 = *(const s16x8*)&pw0[l15*72 + st*32 + quad*8];
        s16x8 pf1 = *(const s16x8*)&pw1[l15*72 + st*32 + quad*8];
#pragma unroll
        for (int dt = 0; dt < 8; dt++) {
          s16x8 vf = *(const s16x8*)&Vt[(dt*16 + l15)*72 + st*32 + quad*8];
          o0[dt] = __builtin_amdgcn_mfma_f32_16x16x32_bf16(vf, pf0, o0[dt], 0, 0, 0);
          o1[dt] = __builtin_amdgcn_mfma_f32_16x16x32_bf16(vf, pf1, o1[dt], 0, 0, 0);
        }
      }
    }

    // finalize li (once per phase), then transpose O^T -> O via wave-private Pt slice
    li0 += __shfl_xor(li0, 16); li0 += __shfl_xor(li0, 32);
    li1 += __shfl_xor(li1, 16); li1 += __shfl_xor(li1, 32);
    const float inv0 = 1.0f / li0, inv1 = 1.0f / li1;

    short* ep = pw0;
#pragma unroll
    for (int g = 0; g < 2; g++) {
      const float inv = g ? inv1 : inv0;
      const f32x4* o = g ? o1 : o0;
      const int qg = g ? q1 : q0;
#pragma unroll
      for (int dt = 0; dt < 8; dt++) {
        union { bf16 h[4]; unsigned long long u; } pk;
        pk.h[0] = __float2bfloat16(o[dt][0]*inv);
        pk.h[1] = __float2bfloat16(o[dt][1]*inv);
        pk.h[2] = __float2bfloat16(o[dt][2]*inv);
        pk.h[3] = __float2bfloat16(o[dt][3]*inv);
        *(unsigned long long*)&ep[l15*136 + dt*16 + quad*4] = pk.u;
      }
      bf16* yb = Yb + ((long)(b*SEQ + qg - l15))*DIM + h*HD;
#pragma unroll
      for (int p = 0; p < 4; p++) {
        const int c = quad + 4*p;
        uint4 yv = *(const uint4*)&ep[l15*136 + c*8];
        *(uint4*)&yb[(long)l15*DIM + c*8] = yv;
      }
    }
  }
}

extern "C" void kernel_launch(void* const* d_in, const int* in_sizes, int n_in,
                              void* d_out, int out_size, void* d_ws, size_t ws_size,
                              hipStream_t stream) {
  (void)in_sizes; (void)n_in; (void)out_size; (void)ws_size;
  const float* x   = (const float*)d_in[0];
  const float* Wq  = (const float*)d_in[1];
  const float* Wk  = (const float*)d_in[2];
  const float* Wv  = (const float*)d_in[3];
  const float* Wo  = (const float*)d_in[4];
  const float* qg  = (const float*)d_in[5];

  char* ws = (char*)d_ws;
  bf16* xbf  = (bf16*)(ws);                         // 32 MB
  bf16* Wqkv = (bf16*)(ws + 33554432);              // 12 MB
  bf16* Wob  = (bf16*)(ws + 46137344);              //  8 MB
  bf16* Qb   = (bf16*)(ws + 54525952);              // 32 MB
  bf16* Kb   = (bf16*)(ws + 88080384);              //  8 MB
  bf16* Vb   = (bf16*)(ws + 96468992);              //  8 MB (transposed [b,kvh,d,s])
  bf16* Yb   = (bf16*)(ws + 104857600);             // 32 MB

  cast_all<<<13312, 256, 0, stream>>>(x, Wq, Wk, Wv, Wo, xbf, Wqkv, Wob);

  gemm8<1><<<dim3(NQKV/256, MROWS/256), 512, 0, stream>>>(
      xbf, Wqkv, nullptr, Qb, Kb, Vb, NQKV, DIM);

  norm_rope<<<40960, 256, 0, stream>>>(Qb, Kb, qg);

  attn<<<dim3(8, BSZ*NHEADS), 256, 0, stream>>>(Qb, Kb, Vb, Yb);

  gemm8<0><<<dim3(DIM/256, MROWS/256), 512, 0, stream>>>(
      Yb, Wob, (float*)d_out, nullptr, nullptr, nullptr, DIM, DIM);
}